// Round 1
// baseline (121.432 us; speedup 1.0000x reference)
//
#include <hip/hip_runtime.h>

#define N_DIM   8
#define N_COMP  4
#define N_SYMB  16
#define TBL     (N_SYMB * N_COMP * N_DIM)   // 512

__global__ __launch_bounds__(256) void inv_affine_kernel(
    const float4* __restrict__ samples4,   // (n, 2) float4 per row
    const float*  __restrict__ mus_orig,   // (16, 32)
    const float*  __restrict__ mus,        // (16, 32)
    const float*  __restrict__ psi,        // (32,)
    const int*    __restrict__ idx_symb,   // (n,)
    const int*    __restrict__ idx_comp,   // (n,)
    float4*       __restrict__ out4,       // (n, 2) float4 per row
    int n)
{
    __shared__ float s_invpsi[N_COMP * N_DIM];   // 32 floats
    __shared__ float s_off[TBL];                 // 512 floats

    const int tid = threadIdx.x;

    // Stage 1: reciprocal of psi
    if (tid < N_COMP * N_DIM) {
        s_invpsi[tid] = 1.0f / psi[tid];
    }
    __syncthreads();

    // Stage 2: fused offset table  off = mu_orig - mu * invpsi
    for (int i = tid; i < TBL; i += blockDim.x) {
        const int cd = i & (N_COMP * N_DIM - 1);   // i % 32
        s_off[i] = fmaf(-mus[i], s_invpsi[cd], mus_orig[i]);
    }
    __syncthreads();

    // Main grid-stride loop: one row (8 floats) per thread per iteration
    const long long total  = n;
    const long long stride = (long long)gridDim.x * blockDim.x;
    for (long long row = (long long)blockIdx.x * blockDim.x + tid;
         row < total; row += stride) {
        const int symb = idx_symb[row];
        const int comp = idx_comp[row];
        const int base = (symb * N_COMP + comp) * N_DIM;
        const int pb   = comp * N_DIM;

        const float4 s0 = samples4[row * 2 + 0];
        const float4 s1 = samples4[row * 2 + 1];

        float4 o0, o1;
        o0.x = fmaf(s0.x, s_invpsi[pb + 0], s_off[base + 0]);
        o0.y = fmaf(s0.y, s_invpsi[pb + 1], s_off[base + 1]);
        o0.z = fmaf(s0.z, s_invpsi[pb + 2], s_off[base + 2]);
        o0.w = fmaf(s0.w, s_invpsi[pb + 3], s_off[base + 3]);
        o1.x = fmaf(s1.x, s_invpsi[pb + 4], s_off[base + 4]);
        o1.y = fmaf(s1.y, s_invpsi[pb + 5], s_off[base + 5]);
        o1.z = fmaf(s1.z, s_invpsi[pb + 6], s_off[base + 6]);
        o1.w = fmaf(s1.w, s_invpsi[pb + 7], s_off[base + 7]);

        out4[row * 2 + 0] = o0;
        out4[row * 2 + 1] = o1;
    }
}

extern "C" void kernel_launch(void* const* d_in, const int* in_sizes, int n_in,
                              void* d_out, int out_size, void* d_ws, size_t ws_size,
                              hipStream_t stream) {
    const float4* samples4 = (const float4*)d_in[0];
    const float*  mus_orig = (const float*)d_in[1];
    const float*  mus      = (const float*)d_in[2];
    const float*  psi      = (const float*)d_in[3];
    const int*    idx_symb = (const int*)d_in[4];
    const int*    idx_comp = (const int*)d_in[5];
    float4*       out4     = (float4*)d_out;

    const int n = in_sizes[4];   // number of sample rows (idx_symb length)

    const int threads = 256;
    int blocks = (n + threads - 1) / threads;
    if (blocks > 4096) blocks = 4096;   // grid-stride caps launch size

    inv_affine_kernel<<<blocks, threads, 0, stream>>>(
        samples4, mus_orig, mus, psi, idx_symb, idx_comp, out4, n);
}